// Round 1
// baseline (55.423 us; speedup 1.0000x reference)
//
#include <hip/hip_runtime.h>

// Problem constants (fixed shapes per reference).
constexpr int N    = 336000;      // anchors
constexpr int NG   = N / 4;       // float4 groups = 84000
constexpr int CBOX = 4;           // channels 0..3 = boxes, 4..83 = logits
constexpr int KSEL = 6720;        // int(N * 0.02)
constexpr float CONFTH = 0.2f;

constexpr int   NB      = 4096;
constexpr float LO      = -16.0f;
constexpr float BW1     = 32.0f / NB;      // 0.0078125
constexpr float INV_BW1 = NB / 32.0f;      // 128
constexpr float BW2     = BW1 / NB;        // ~1.907e-6
constexpr float INV_BW2 = NB / BW1;        // 524288

__device__ __forceinline__ int bin1(float s) {
  int b = (int)floorf((s - LO) * INV_BW1);
  return b < 0 ? 0 : (b > NB - 1 ? NB - 1 : b);
}

// K1: scores = max over logit channels; build coarse histogram.
__global__ __launch_bounds__(256)
void k1_scores(const float* __restrict__ in, float* __restrict__ scores,
               int* __restrict__ hist1) {
  __shared__ int lh[NB];
  for (int i = threadIdx.x; i < NB; i += 256) lh[i] = 0;
  __syncthreads();

  int j = blockIdx.x * 256 + threadIdx.x;
  if (j < NG) {
    const float* p = in + (size_t)CBOX * N + 4 * j;
    float4 m = *(const float4*)p;
#pragma unroll 8
    for (int c = 1; c < 80; ++c) {
      float4 v = *(const float4*)(p + (size_t)c * N);
      m.x = fmaxf(m.x, v.x);
      m.y = fmaxf(m.y, v.y);
      m.z = fmaxf(m.z, v.z);
      m.w = fmaxf(m.w, v.w);
    }
    *(float4*)(scores + 4 * j) = m;
    atomicAdd(&lh[bin1(m.x)], 1);
    atomicAdd(&lh[bin1(m.y)], 1);
    atomicAdd(&lh[bin1(m.z)], 1);
    atomicAdd(&lh[bin1(m.w)], 1);
  }
  __syncthreads();
  for (int i = threadIdx.x; i < NB; i += 256) {
    int v = lh[i];
    if (v) atomicAdd(&hist1[i], v);
  }
}

// K2: suffix-scan coarse histogram; find boundary bin b1 and residual rank r.
__global__ __launch_bounds__(1024)
void k2_sel(const int* __restrict__ hist1, int* __restrict__ ctrl) {
  __shared__ int sa[NB], sb[NB];
  int t = threadIdx.x;
  for (int i = t; i < NB; i += 1024) sa[i] = hist1[i];
  __syncthreads();
  int* src = sa;
  int* dst = sb;
  for (int d = 1; d < NB; d <<= 1) {
    for (int i = t; i < NB; i += 1024)
      dst[i] = src[i] + ((i + d < NB) ? src[i + d] : 0);
    __syncthreads();
    int* tmp = src; src = dst; dst = tmp;
  }
  for (int i = t; i < NB; i += 1024) {
    int Si = src[i];
    int Sn = (i + 1 < NB) ? src[i + 1] : 0;
    if (Si >= KSEL && Sn < KSEL) {
      ctrl[0] = i;            // boundary bin
      ctrl[1] = KSEL - Sn;    // how many still needed from inside bin i (>=1)
    }
  }
}

// K3: refine — histogram the boundary bin's elements into NB sub-bins.
__global__ __launch_bounds__(256)
void k3_refine(const float* __restrict__ scores, const int* __restrict__ ctrl,
               int* __restrict__ hist2) {
  int b1 = ctrl[0];
  float lo2 = LO + b1 * BW1;
  int j = blockIdx.x * 256 + threadIdx.x;
  if (j >= NG) return;
  float4 s = ((const float4*)scores)[j];
  float v[4] = {s.x, s.y, s.z, s.w};
#pragma unroll
  for (int q = 0; q < 4; ++q) {
    if (bin1(v[q]) == b1) {
      int b2 = (int)floorf((v[q] - lo2) * INV_BW2);
      b2 = b2 < 0 ? 0 : (b2 > NB - 1 ? NB - 1 : b2);
      atomicAdd(&hist2[b2], 1);
    }
  }
}

// K4: scan refinement histogram -> final float threshold T (>= CONF).
__global__ __launch_bounds__(1024)
void k4_sel2(const int* __restrict__ hist2, int* __restrict__ ctrl) {
  __shared__ int sa[NB], sb[NB];
  int t = threadIdx.x;
  int b1 = ctrl[0];
  int r  = ctrl[1];
  for (int i = t; i < NB; i += 1024) sa[i] = hist2[i];
  __syncthreads();
  int* src = sa;
  int* dst = sb;
  for (int d = 1; d < NB; d <<= 1) {
    for (int i = t; i < NB; i += 1024)
      dst[i] = src[i] + ((i + d < NB) ? src[i + d] : 0);
    __syncthreads();
    int* tmp = src; src = dst; dst = tmp;
  }
  for (int i = t; i < NB; i += 1024) {
    int Si = src[i];
    int Sn = (i + 1 < NB) ? src[i + 1] : 0;
    if (Si >= r && Sn < r) {
      float T = (LO + b1 * BW1) + i * BW2;
      ((float*)ctrl)[2] = fmaxf(T, CONFTH);
    }
  }
}

// K5: final sum of selected scores + their 4 box coords.
__global__ __launch_bounds__(256)
void k5_sum(const float* __restrict__ in, const float* __restrict__ scores,
            const int* __restrict__ ctrl, float* __restrict__ out) {
  float Tf = ((const float*)ctrl)[2];
  int j = blockIdx.x * 256 + threadIdx.x;
  float acc = 0.0f;
  if (j < NG) {
    float4 s = ((const float4*)scores)[j];
    float v[4] = {s.x, s.y, s.z, s.w};
#pragma unroll
    for (int q = 0; q < 4; ++q) {
      if (v[q] >= Tf) {
        int i = 4 * j + q;
        acc += v[q] + in[i] + in[N + i] + in[2 * N + i] + in[3 * N + i];
      }
    }
  }
  for (int off = 32; off > 0; off >>= 1) acc += __shfl_down(acc, off);
  __shared__ float wsum[4];
  if ((threadIdx.x & 63) == 0) wsum[threadIdx.x >> 6] = acc;
  __syncthreads();
  if (threadIdx.x == 0) atomicAdd(out, wsum[0] + wsum[1] + wsum[2] + wsum[3]);
}

extern "C" void kernel_launch(void* const* d_in, const int* in_sizes, int n_in,
                              void* d_out, int out_size, void* d_ws, size_t ws_size,
                              hipStream_t stream) {
  const float* in = (const float*)d_in[0];
  float* out = (float*)d_out;

  // ws layout: scores[N] floats | hist1[NB] | hist2[NB] | ctrl[8]
  float* scores = (float*)d_ws;
  int* hist1 = (int*)((char*)d_ws + (size_t)N * sizeof(float));
  int* hist2 = hist1 + NB;
  int* ctrl  = hist2 + NB;

  hipMemsetAsync(hist1, 0, (2 * NB + 8) * sizeof(int), stream);
  hipMemsetAsync(d_out, 0, sizeof(float), stream);

  int blocks = (NG + 255) / 256;
  k1_scores<<<blocks, 256, 0, stream>>>(in, scores, hist1);
  k2_sel<<<1, 1024, 0, stream>>>(hist1, ctrl);
  k3_refine<<<blocks, 256, 0, stream>>>(scores, ctrl, hist2);
  k4_sel2<<<1, 1024, 0, stream>>>(hist2, ctrl);
  k5_sum<<<blocks, 256, 0, stream>>>(in, scores, ctrl, out);
}